// Round 3
// baseline (3006.289 us; speedup 1.0000x reference)
//
#include <hip/hip_runtime.h>

#define D_IN  256
#define D_HID 512
#define NEG_SLOPE 0.2f

typedef __attribute__((ext_vector_type(8))) short short8;
typedef __attribute__((ext_vector_type(4))) float floatx4;

__device__ __forceinline__ unsigned short f2bf(float f) {
    unsigned int u = __float_as_uint(f);
    u += 0x7fffu + ((u >> 16) & 1u);   // round-to-nearest-even
    return (unsigned short)(u >> 16);
}
__device__ __forceinline__ float bf2f(unsigned short u) {
    return __uint_as_float(((unsigned int)u) << 16);
}

// edge_index accessor: is64 selects int64 vs int32 element stride
__device__ __forceinline__ int eidx(const void* ei, long pos, int is64) {
    return is64 ? (int)((const long long*)ei)[pos] : ((const int*)ei)[pos];
}

// ---------------- dtype detect: int64 iff sampled odd 32-bit words are all zero ----------------
__global__ void k_detect(const unsigned int* __restrict__ ei, int npairs, int* flag) {
    __shared__ int nz;
    if (threadIdx.x == 0) nz = 0;
    __syncthreads();
    for (int i = threadIdx.x; i < npairs; i += blockDim.x)
        if (ei[2 * i + 1] != 0) nz = 1;
    __syncthreads();
    if (threadIdx.x == 0) *flag = nz ? 0 : 1;   // 1 => int64
}

// ---------------- degree / norm ----------------
__global__ void k_deg_init(float* dinv, int N) {
    int i = blockIdx.x * blockDim.x + threadIdx.x;
    if (i < N) dinv[i] = 1.0f;   // self-loop
}

__global__ void k_deg_count(const void* __restrict__ ei, const int* __restrict__ flag,
                            float* dinv, int E) {
    int e = blockIdx.x * blockDim.x + threadIdx.x;
    if (e < E) atomicAdd(&dinv[eidx(ei, (long)E + e, *flag)], 1.0f);
}

__global__ void k_rsqrt(float* dinv, int N) {
    int i = blockIdx.x * blockDim.x + threadIdx.x;
    if (i < N) dinv[i] = rsqrtf(dinv[i]);
}

// ---------------- aggregation: agg = Â x  (fp32) ----------------
__global__ void k_agg_init(const float* __restrict__ x, const float* __restrict__ dinv,
                           float* __restrict__ agg, int N) {
    int t = blockIdx.x * blockDim.x + threadIdx.x;   // N*64 threads
    int i = t >> 6, c = t & 63;
    if (i >= N) return;
    float w = dinv[i]; w = w * w;                    // self-loop norm
    float4 v = ((const float4*)x)[(long)i * 64 + c];
    v.x *= w; v.y *= w; v.z *= w; v.w *= w;
    ((float4*)agg)[(long)i * 64 + c] = v;
}

__global__ __launch_bounds__(256) void k_scatter(const float* __restrict__ x,
                                                 const void* __restrict__ ei,
                                                 const int* __restrict__ flag,
                                                 const float* __restrict__ dinv,
                                                 float* __restrict__ agg, int E) {
    long t = (long)blockIdx.x * blockDim.x + threadIdx.x;  // E*64 threads
    int e = (int)(t >> 6), lane = (int)(t & 63);
    if (e >= E) return;
    int is64 = *flag;
    int s = eidx(ei, e, is64), d = eidx(ei, (long)E + e, is64);
    float w = dinv[s] * dinv[d];
    float4 v = ((const float4*)x)[(long)s * 64 + lane];
    float* ad = agg + (long)d * D_IN + lane * 4;
    atomicAdd(ad + 0, w * v.x);
    atomicAdd(ad + 1, w * v.y);
    atomicAdd(ad + 2, w * v.z);
    atomicAdd(ad + 3, w * v.w);
}

// ---------------- fp32 -> bf16 convert ----------------
__global__ void k_f2bf(const float* __restrict__ in, unsigned short* __restrict__ out, long n) {
    long t = (long)blockIdx.x * blockDim.x + threadIdx.x;  // n/4 threads
    long i = t * 4;
    if (i >= n) return;
    float4 v = *(const float4*)(in + i);
    ushort4 o;
    o.x = f2bf(v.x); o.y = f2bf(v.y); o.z = f2bf(v.z); o.w = f2bf(v.w);
    *(ushort4*)(out + i) = o;
}

// W [K,N] fp32 -> Wt [N,K] bf16
__global__ void k_wt(const float* __restrict__ W, unsigned short* __restrict__ Wt, int K, int N) {
    int t = blockIdx.x * blockDim.x + threadIdx.x;
    if (t >= K * N) return;
    int n = t / K, k = t - n * K;
    Wt[(long)n * K + k] = f2bf(W[(long)k * N + n]);
}

// ---------------- bf16 MFMA GEMM: C[M,512] = leaky(A[M,K] @ Bt[512,K]^T + bias) ----------------
__device__ __forceinline__ void async_cp16(const unsigned short* gp, unsigned short* lp) {
    __builtin_amdgcn_global_load_lds((const __attribute__((address_space(1))) void*)gp,
                                     (__attribute__((address_space(3))) void*)lp, 16, 0, 0);
}

__global__ __launch_bounds__(256) void k_gemm_bf16(const unsigned short* __restrict__ A,
                                                   const unsigned short* __restrict__ Bt,
                                                   const float* __restrict__ bias,
                                                   unsigned short* __restrict__ C,
                                                   int M, int K) {
    __shared__ __align__(16) unsigned short As[128 * 32];   // [m][k], 64B rows
    __shared__ __align__(16) unsigned short Bs[128 * 32];   // [n][k], 64B rows
    const int tid  = threadIdx.x;
    const int lane = tid & 63, wave = tid >> 6;
    const int m0 = blockIdx.x * 128, n0 = blockIdx.y * 128;
    const int r = lane & 15, q = lane >> 4;
    const int wm = (wave & 1) * 64, wn = (wave >> 1) * 64;

    floatx4 acc[4][4];
#pragma unroll
    for (int i = 0; i < 4; ++i)
#pragma unroll
        for (int j = 0; j < 4; ++j) acc[i][j] = (floatx4){0.f, 0.f, 0.f, 0.f};

    for (int k0 = 0; k0 < K; k0 += 32) {
        // stage A tile (128m x 32k) and B tile (128n x 32k) as 16B chunks.
        // 32 bf16 = 64 B = FOUR 16B chunks per row; 128 rows * 4 = 512 chunks.
#pragma unroll
        for (int i = 0; i < 2; ++i) {
            int c = i * 256 + tid;          // chunk 0..511
            int row = c >> 2, qtr = c & 3;  // 4 chunks per 32-elem row
            int gm = m0 + row; if (gm >= M) gm = M - 1;
            async_cp16(A + (long)gm * K + k0 + qtr * 8, As + c * 8);
        }
#pragma unroll
        for (int i = 0; i < 2; ++i) {
            int c = i * 256 + tid;
            int row = c >> 2, qtr = c & 3;
            async_cp16(Bt + (long)(n0 + row) * K + k0 + qtr * 8, Bs + c * 8);
        }
        __syncthreads();   // drains vmcnt before barrier

        short8 af[4], bf[4];
#pragma unroll
        for (int i = 0; i < 4; ++i)
            af[i] = *(const short8*)(As + (wm + i * 16 + r) * 32 + q * 8);
#pragma unroll
        for (int j = 0; j < 4; ++j)
            bf[j] = *(const short8*)(Bs + (wn + j * 16 + r) * 32 + q * 8);
#pragma unroll
        for (int i = 0; i < 4; ++i)
#pragma unroll
            for (int j = 0; j < 4; ++j)
                acc[i][j] = __builtin_amdgcn_mfma_f32_16x16x32_bf16(af[i], bf[j], acc[i][j], 0, 0, 0);
        __syncthreads();
    }

    // epilogue: bias + leaky relu, bf16 store.  C/D map: col = lane&15, row = q*4 + reg
#pragma unroll
    for (int j = 0; j < 4; ++j) {
        int col = n0 + wn + j * 16 + r;
        float bv = bias[col];
#pragma unroll
        for (int i = 0; i < 4; ++i) {
#pragma unroll
            for (int t2 = 0; t2 < 4; ++t2) {
                int row = m0 + wm + i * 16 + q * 4 + t2;
                if (row < M) {
                    float v = acc[i][j][t2] + bv;
                    v = v > 0.f ? v : NEG_SLOPE * v;
                    C[(long)row * D_HID + col] = f2bf(v);
                }
            }
        }
    }
}

// ---------------- head: out[m] = h2[m,:] . wout + b ----------------
__global__ __launch_bounds__(256) void k_rowdot(const unsigned short* __restrict__ h2,
                                                const float* __restrict__ wout,
                                                const float* __restrict__ bout,
                                                float* __restrict__ out, int N) {
    int row = blockIdx.x * (blockDim.x >> 6) + (threadIdx.x >> 6);
    int lane = threadIdx.x & 63;
    if (row >= N) return;
    short8 hv = *(const short8*)(h2 + (long)row * D_HID + lane * 8);
    float s = 0.f;
#pragma unroll
    for (int j = 0; j < 8; ++j)
        s += bf2f((unsigned short)hv[j]) * wout[lane * 8 + j];
#pragma unroll
    for (int off = 32; off > 0; off >>= 1) s += __shfl_down(s, off, 64);
    if (lane == 0) out[row] = s + bout[0];
}

extern "C" void kernel_launch(void* const* d_in, const int* in_sizes, int n_in,
                              void* d_out, int out_size, void* d_ws, size_t ws_size,
                              hipStream_t stream) {
    const float* x     = (const float*)d_in[0];
    const void*  ei    = d_in[1];
    const float* W_gcn = (const float*)d_in[2];
    const float* b_gcn = (const float*)d_in[3];
    const float* W2    = (const float*)d_in[4];
    const float* b2    = (const float*)d_in[5];
    const float* W_out = (const float*)d_in[6];
    const float* b_out = (const float*)d_in[7];
    float* out = (float*)d_out;

    const int N = in_sizes[0] / D_IN;
    const int E = in_sizes[1] / 2;

    // workspace layout
    char* w = (char*)d_ws;
    size_t off = 0;
    auto alloc = [&](size_t bytes) { char* p = w + off; off = (off + bytes + 255) & ~(size_t)255; return p; };
    int*            flag = (int*)alloc(256);
    float*          dinv = (float*)alloc((size_t)N * 4);
    float*          agg  = (float*)alloc((size_t)N * D_IN * 4);       // later reused as h1
    unsigned short* aggb = (unsigned short*)alloc((size_t)N * D_IN * 2);
    unsigned short* h2   = (unsigned short*)alloc((size_t)N * D_HID * 2);
    unsigned short* Wgt  = (unsigned short*)alloc((size_t)D_IN * D_HID * 2);
    unsigned short* W2t  = (unsigned short*)alloc((size_t)D_HID * D_HID * 2);
    unsigned short* h1   = (unsigned short*)agg;  // reuse: GEMM1 reads aggb, writes h1

    int npairs = E < 2048 ? E : 2048;   // sample first npairs (32b-word pairs)
    k_detect<<<1, 256, 0, stream>>>((const unsigned int*)ei, npairs, flag);

    k_deg_init<<<(N + 255) / 256, 256, 0, stream>>>(dinv, N);
    k_deg_count<<<(E + 255) / 256, 256, 0, stream>>>(ei, flag, dinv, E);
    k_rsqrt<<<(N + 255) / 256, 256, 0, stream>>>(dinv, N);

    k_agg_init<<<((long)N * 64 + 255) / 256, 256, 0, stream>>>(x, dinv, agg, N);
    k_scatter<<<(unsigned)(((long)E * 64 + 255) / 256), 256, 0, stream>>>(x, ei, flag, dinv, agg, E);

    k_f2bf<<<(unsigned)(((long)N * D_IN / 4 + 255) / 256), 256, 0, stream>>>(agg, aggb, (long)N * D_IN);
    k_wt<<<(D_IN * D_HID + 255) / 256, 256, 0, stream>>>(W_gcn, Wgt, D_IN, D_HID);
    k_wt<<<(D_HID * D_HID + 255) / 256, 256, 0, stream>>>(W2, W2t, D_HID, D_HID);

    dim3 g1((N + 127) / 128, D_HID / 128);
    k_gemm_bf16<<<g1, 256, 0, stream>>>(aggb, Wgt, b_gcn, h1, N, D_IN);
    k_gemm_bf16<<<g1, 256, 0, stream>>>(h1, W2t, b2, h2, N, D_HID);

    k_rowdot<<<(N + 3) / 4, 256, 0, stream>>>(h2, W_out, b_out, out, N);
}

// Round 4
// 596.752 us; speedup vs baseline: 5.0378x; 5.0378x over previous
//
#include <hip/hip_runtime.h>

#define D_IN  256
#define D_HID 512
#define NEG_SLOPE 0.2f

typedef __attribute__((ext_vector_type(8))) short short8;
typedef __attribute__((ext_vector_type(4))) float floatx4;

__device__ __forceinline__ unsigned short f2bf(float f) {
    unsigned int u = __float_as_uint(f);
    u += 0x7fffu + ((u >> 16) & 1u);   // round-to-nearest-even
    return (unsigned short)(u >> 16);
}
__device__ __forceinline__ float bf2f(unsigned short u) {
    return __uint_as_float(((unsigned int)u) << 16);
}

// edge_index accessor: is64 selects int64 vs int32 element stride
__device__ __forceinline__ int eidx(const void* ei, long pos, int is64) {
    return is64 ? (int)((const long long*)ei)[pos] : ((const int*)ei)[pos];
}

// ---------------- dtype detect: int64 iff sampled odd 32-bit words are all zero ----------------
__global__ void k_detect(const unsigned int* __restrict__ ei, int npairs, int* flag) {
    __shared__ int nz;
    if (threadIdx.x == 0) nz = 0;
    __syncthreads();
    for (int i = threadIdx.x; i < npairs; i += blockDim.x)
        if (ei[2 * i + 1] != 0) nz = 1;
    __syncthreads();
    if (threadIdx.x == 0) *flag = nz ? 0 : 1;   // 1 => int64
}

// ---------------- degree / norm ----------------
__global__ void k_deg_init(float* dinv, int* deg_i, int N) {
    int i = blockIdx.x * blockDim.x + threadIdx.x;
    if (i < N) { dinv[i] = 1.0f; deg_i[i] = 0; }   // dinv starts at 1 (self-loop)
}

__global__ void k_deg_count(const void* __restrict__ ei, const int* __restrict__ flag,
                            float* dinv, int* deg_i, int E) {
    int e = blockIdx.x * blockDim.x + threadIdx.x;
    if (e < E) {
        int d = eidx(ei, (long)E + e, *flag);
        atomicAdd(&dinv[d], 1.0f);
        atomicAdd(&deg_i[d], 1);
    }
}

__global__ void k_rsqrt(float* dinv, int N) {
    int i = blockIdx.x * blockDim.x + threadIdx.x;
    if (i < N) dinv[i] = rsqrtf(dinv[i]);
}

// ---------------- single-block exclusive scan: offs[0..N], cursor copy ----------------
__global__ __launch_bounds__(1024) void k_scan(const int* __restrict__ deg,
                                               int* __restrict__ offs,
                                               int* __restrict__ cursor, int N) {
    __shared__ int lds[1024];
    const int t = threadIdx.x;
    const int chunk = (N + 1023) / 1024;
    const int lo = t * chunk, hi = min(N, lo + chunk);
    int s = 0;
    for (int i = lo; i < hi; ++i) s += deg[i];
    lds[t] = s;
    __syncthreads();
    for (int d = 1; d < 1024; d <<= 1) {
        int add = (t >= d) ? lds[t - d] : 0;
        __syncthreads();
        lds[t] += add;
        __syncthreads();
    }
    int run = (t > 0) ? lds[t - 1] : 0;
    for (int i = lo; i < hi; ++i) {
        int dv = deg[i];
        offs[i] = run; cursor[i] = run;
        run += dv;
    }
    if (lo < N && hi == N) offs[N] = run;
}

// ---------------- fill CSR edge list (src per slot, dst-sorted) ----------------
__global__ void k_fill(const void* __restrict__ ei, const int* __restrict__ flag,
                       int* __restrict__ cursor, int* __restrict__ esrc, int E) {
    int e = blockIdx.x * blockDim.x + threadIdx.x;
    if (e >= E) return;
    int is64 = *flag;
    int s = eidx(ei, e, is64), d = eidx(ei, (long)E + e, is64);
    int pos = atomicAdd(&cursor[d], 1);
    esrc[pos] = s;
}

// ---------------- gather: aggb[i] = bf16( dinv[i]*(dinv[i]*x[i] + sum dinv[s]*x[s]) ) ----------------
__global__ __launch_bounds__(256) void k_gather(const float* __restrict__ x,
                                                const int* __restrict__ offs,
                                                const int* __restrict__ esrc,
                                                const float* __restrict__ dinv,
                                                unsigned short* __restrict__ aggb, int N) {
    int node = blockIdx.x * 4 + (threadIdx.x >> 6);
    int lane = threadIdx.x & 63;
    if (node >= N) return;
    float di = dinv[node];
    float4 v0 = ((const float4*)x)[(long)node * 64 + lane];
    float ax = di * v0.x, ay = di * v0.y, az = di * v0.z, aw = di * v0.w;
    int beg = offs[node], end = offs[node + 1];
    for (int e = beg; e < end; ++e) {
        int s = esrc[e];                 // wave-uniform broadcast load
        float ws = dinv[s];
        float4 v = ((const float4*)x)[(long)s * 64 + lane];
        ax += ws * v.x; ay += ws * v.y; az += ws * v.z; aw += ws * v.w;
    }
    ax *= di; ay *= di; az *= di; aw *= di;
    ushort4 o; o.x = f2bf(ax); o.y = f2bf(ay); o.z = f2bf(az); o.w = f2bf(aw);
    ((ushort4*)aggb)[(long)node * 64 + lane] = o;
}

// W [K,N] fp32 -> Wt [N,K] bf16
__global__ void k_wt(const float* __restrict__ W, unsigned short* __restrict__ Wt, int K, int N) {
    int t = blockIdx.x * blockDim.x + threadIdx.x;
    if (t >= K * N) return;
    int n = t / K, k = t - n * K;
    Wt[(long)n * K + k] = f2bf(W[(long)k * N + n]);
}

// ---------------- bf16 MFMA GEMM: C[M,512] = leaky(A[M,K] @ Bt[512,K]^T + bias) ----------------
__device__ __forceinline__ void async_cp16(const unsigned short* gp, unsigned short* lp) {
    __builtin_amdgcn_global_load_lds((const __attribute__((address_space(1))) void*)gp,
                                     (__attribute__((address_space(3))) void*)lp, 16, 0, 0);
}

__global__ __launch_bounds__(256) void k_gemm_bf16(const unsigned short* __restrict__ A,
                                                   const unsigned short* __restrict__ Bt,
                                                   const float* __restrict__ bias,
                                                   unsigned short* __restrict__ C,
                                                   int M, int K) {
    __shared__ __align__(16) unsigned short As[128 * 32];   // [m][k], 64B rows
    __shared__ __align__(16) unsigned short Bs[128 * 32];   // [n][k], 64B rows
    const int tid  = threadIdx.x;
    const int lane = tid & 63, wave = tid >> 6;
    const int m0 = blockIdx.x * 128, n0 = blockIdx.y * 128;
    const int r = lane & 15, q = lane >> 4;
    const int wm = (wave & 1) * 64, wn = (wave >> 1) * 64;

    floatx4 acc[4][4];
#pragma unroll
    for (int i = 0; i < 4; ++i)
#pragma unroll
        for (int j = 0; j < 4; ++j) acc[i][j] = (floatx4){0.f, 0.f, 0.f, 0.f};

    for (int k0 = 0; k0 < K; k0 += 32) {
        // stage A tile (128m x 32k) and B tile (128n x 32k) as 16B chunks.
        // 32 bf16 = 64 B = FOUR 16B chunks per row; 128 rows * 4 = 512 chunks.
#pragma unroll
        for (int i = 0; i < 2; ++i) {
            int c = i * 256 + tid;          // chunk 0..511
            int row = c >> 2, qtr = c & 3;  // 4 chunks per 32-elem row
            int gm = m0 + row; if (gm >= M) gm = M - 1;
            async_cp16(A + (long)gm * K + k0 + qtr * 8, As + c * 8);
        }
#pragma unroll
        for (int i = 0; i < 2; ++i) {
            int c = i * 256 + tid;
            int row = c >> 2, qtr = c & 3;
            async_cp16(Bt + (long)(n0 + row) * K + k0 + qtr * 8, Bs + c * 8);
        }
        __syncthreads();   // drains vmcnt before barrier

        short8 af[4], bf[4];
#pragma unroll
        for (int i = 0; i < 4; ++i)
            af[i] = *(const short8*)(As + (wm + i * 16 + r) * 32 + q * 8);
#pragma unroll
        for (int j = 0; j < 4; ++j)
            bf[j] = *(const short8*)(Bs + (wn + j * 16 + r) * 32 + q * 8);
#pragma unroll
        for (int i = 0; i < 4; ++i)
#pragma unroll
            for (int j = 0; j < 4; ++j)
                acc[i][j] = __builtin_amdgcn_mfma_f32_16x16x32_bf16(af[i], bf[j], acc[i][j], 0, 0, 0);
        __syncthreads();
    }

    // epilogue: bias + leaky relu, bf16 store.  C/D map: col = lane&15, row = q*4 + reg
#pragma unroll
    for (int j = 0; j < 4; ++j) {
        int col = n0 + wn + j * 16 + r;
        float bv = bias[col];
#pragma unroll
        for (int i = 0; i < 4; ++i) {
#pragma unroll
            for (int t2 = 0; t2 < 4; ++t2) {
                int row = m0 + wm + i * 16 + q * 4 + t2;
                if (row < M) {
                    float v = acc[i][j][t2] + bv;
                    v = v > 0.f ? v : NEG_SLOPE * v;
                    C[(long)row * D_HID + col] = f2bf(v);
                }
            }
        }
    }
}

// ---------------- head: out[m] = h2[m,:] . wout + b ----------------
__global__ __launch_bounds__(256) void k_rowdot(const unsigned short* __restrict__ h2,
                                                const float* __restrict__ wout,
                                                const float* __restrict__ bout,
                                                float* __restrict__ out, int N) {
    int row = blockIdx.x * (blockDim.x >> 6) + (threadIdx.x >> 6);
    int lane = threadIdx.x & 63;
    if (row >= N) return;
    short8 hv = *(const short8*)(h2 + (long)row * D_HID + lane * 8);
    float s = 0.f;
#pragma unroll
    for (int j = 0; j < 8; ++j)
        s += bf2f((unsigned short)hv[j]) * wout[lane * 8 + j];
#pragma unroll
    for (int off = 32; off > 0; off >>= 1) s += __shfl_down(s, off, 64);
    if (lane == 0) out[row] = s + bout[0];
}

extern "C" void kernel_launch(void* const* d_in, const int* in_sizes, int n_in,
                              void* d_out, int out_size, void* d_ws, size_t ws_size,
                              hipStream_t stream) {
    const float* x     = (const float*)d_in[0];
    const void*  ei    = d_in[1];
    const float* W_gcn = (const float*)d_in[2];
    const float* b_gcn = (const float*)d_in[3];
    const float* W2    = (const float*)d_in[4];
    const float* b2    = (const float*)d_in[5];
    const float* W_out = (const float*)d_in[6];
    const float* b_out = (const float*)d_in[7];
    float* out = (float*)d_out;

    const int N = in_sizes[0] / D_IN;
    const int E = in_sizes[1] / 2;

    // workspace layout (~133 MB)
    char* w = (char*)d_ws;
    size_t off = 0;
    auto alloc = [&](size_t bytes) { char* p = w + off; off = (off + bytes + 255) & ~(size_t)255; return p; };
    int*            flag  = (int*)alloc(256);
    float*          dinv  = (float*)alloc((size_t)N * 4);
    int*            deg_i = (int*)alloc((size_t)N * 4);
    int*            offs  = (int*)alloc((size_t)(N + 1) * 4);
    int*            cursor= (int*)alloc((size_t)N * 4);
    int*            esrc  = (int*)alloc((size_t)E * 4);
    unsigned short* aggb  = (unsigned short*)alloc((size_t)N * D_IN * 2);
    unsigned short* h1    = (unsigned short*)alloc((size_t)N * D_HID * 2);
    unsigned short* h2    = (unsigned short*)alloc((size_t)N * D_HID * 2);
    unsigned short* Wgt   = (unsigned short*)alloc((size_t)D_IN * D_HID * 2);
    unsigned short* W2t   = (unsigned short*)alloc((size_t)D_HID * D_HID * 2);

    int npairs = E < 2048 ? E : 2048;
    k_detect<<<1, 256, 0, stream>>>((const unsigned int*)ei, npairs, flag);

    k_deg_init<<<(N + 255) / 256, 256, 0, stream>>>(dinv, deg_i, N);
    k_deg_count<<<(E + 255) / 256, 256, 0, stream>>>(ei, flag, dinv, deg_i, E);
    k_rsqrt<<<(N + 255) / 256, 256, 0, stream>>>(dinv, N);

    k_scan<<<1, 1024, 0, stream>>>(deg_i, offs, cursor, N);
    k_fill<<<(E + 255) / 256, 256, 0, stream>>>(ei, flag, cursor, esrc, E);
    k_gather<<<(N + 3) / 4, 256, 0, stream>>>(x, offs, esrc, dinv, aggb, N);

    k_wt<<<(D_IN * D_HID + 255) / 256, 256, 0, stream>>>(W_gcn, Wgt, D_IN, D_HID);
    k_wt<<<(D_HID * D_HID + 255) / 256, 256, 0, stream>>>(W2, W2t, D_HID, D_HID);

    dim3 g1((N + 127) / 128, D_HID / 128);
    k_gemm_bf16<<<g1, 256, 0, stream>>>(aggb, Wgt, b_gcn, h1, N, D_IN);
    k_gemm_bf16<<<g1, 256, 0, stream>>>(h1, W2t, b2, h2, N, D_HID);

    k_rowdot<<<(N + 3) / 4, 256, 0, stream>>>(h2, W_out, b_out, out, N);
}

// Round 6
// 500.334 us; speedup vs baseline: 6.0086x; 1.1927x over previous
//
#include <hip/hip_runtime.h>

#define D_IN  256
#define D_HID 512
#define NEG_SLOPE 0.2f

typedef __attribute__((ext_vector_type(8))) short short8;
typedef __attribute__((ext_vector_type(4))) float floatx4;

__device__ __forceinline__ unsigned short f2bf(float f) {
    unsigned int u = __float_as_uint(f);
    u += 0x7fffu + ((u >> 16) & 1u);   // round-to-nearest-even
    return (unsigned short)(u >> 16);
}
__device__ __forceinline__ float bf2f(unsigned short u) {
    return __uint_as_float(((unsigned int)u) << 16);
}

__device__ __forceinline__ int eidx(const void* ei, long pos, int is64) {
    return is64 ? (int)((const long long*)ei)[pos] : ((const int*)ei)[pos];
}

// ---- init: convert x -> bf16, zero deg, detect edge dtype (block 0) ----
__global__ __launch_bounds__(256) void k_init(const float* __restrict__ x,
                                              unsigned short* __restrict__ xb,
                                              int* __restrict__ deg, int N,
                                              const unsigned int* __restrict__ ei,
                                              int npairs, int* flag) {
    long t = (long)blockIdx.x * blockDim.x + threadIdx.x;
    long i = t * 4;
    long tot = (long)N * D_IN;
    if (i < tot) {
        float4 v = *(const float4*)(x + i);
        ushort4 o;
        o.x = f2bf(v.x); o.y = f2bf(v.y); o.z = f2bf(v.z); o.w = f2bf(v.w);
        *(ushort4*)(xb + i) = o;
    }
    if (t < N) deg[t] = 0;
    if (blockIdx.x == 0) {
        __shared__ int nz;
        if (threadIdx.x == 0) nz = 0;
        __syncthreads();
        for (int p = threadIdx.x; p < npairs; p += blockDim.x)
            if (ei[2 * p + 1] != 0) nz = 1;
        __syncthreads();
        if (threadIdx.x == 0) *flag = nz ? 0 : 1;   // 1 => int64
    }
}

// ---- degree count (int only) ----
__global__ void k_deg_count(const void* __restrict__ ei, const int* __restrict__ flag,
                            int* __restrict__ deg, int E) {
    int e = blockIdx.x * blockDim.x + threadIdx.x;
    if (e < E) atomicAdd(&deg[eidx(ei, (long)E + e, *flag)], 1);
}

// ---- single-block scan: offs/cursor + dinv = rsqrt(1+deg) ----
__global__ __launch_bounds__(1024) void k_scan(const int* __restrict__ deg,
                                               int* __restrict__ offs,
                                               int* __restrict__ cursor,
                                               float* __restrict__ dinv, int N) {
    __shared__ int lds[1024];
    const int t = threadIdx.x;
    const int chunk = (N + 1023) / 1024;
    const int lo = t * chunk, hi = min(N, lo + chunk);
    int s = 0;
    for (int i = lo; i < hi; ++i) s += deg[i];
    lds[t] = s;
    __syncthreads();
    for (int d = 1; d < 1024; d <<= 1) {
        int add = (t >= d) ? lds[t - d] : 0;
        __syncthreads();
        lds[t] += add;
        __syncthreads();
    }
    int run = (t > 0) ? lds[t - 1] : 0;
    for (int i = lo; i < hi; ++i) {
        int dv = deg[i];
        offs[i] = run; cursor[i] = run;
        dinv[i] = rsqrtf(1.0f + (float)dv);
        run += dv;
    }
    if (lo < N && hi == N) offs[N] = run;
}

// ---- fill CSR edge list (src per slot, dst-sorted) ----
__global__ void k_fill(const void* __restrict__ ei, const int* __restrict__ flag,
                       int* __restrict__ cursor, int* __restrict__ esrc, int E) {
    int e = blockIdx.x * blockDim.x + threadIdx.x;
    if (e >= E) return;
    int is64 = *flag;
    int s = eidx(ei, e, is64), d = eidx(ei, (long)E + e, is64);
    int pos = atomicAdd(&cursor[d], 1);
    esrc[pos] = s;
}

// ---- gather (bf16 rows): aggb[i] = bf16( dinv_i*(dinv_i*xb[i] + sum dinv_s*xb[s]) ) ----
__global__ __launch_bounds__(256) void k_gather(const unsigned short* __restrict__ xb,
                                                const int* __restrict__ offs,
                                                const int* __restrict__ esrc,
                                                const float* __restrict__ dinv,
                                                unsigned short* __restrict__ aggb, int N) {
    int node = blockIdx.x * 4 + (threadIdx.x >> 6);
    int lane = threadIdx.x & 63;
    if (node >= N) return;
    float di = dinv[node];
    ushort4 u0 = ((const ushort4*)xb)[(long)node * 64 + lane];
    float ax = di * bf2f(u0.x), ay = di * bf2f(u0.y), az = di * bf2f(u0.z), aw = di * bf2f(u0.w);
    int beg = offs[node], end = offs[node + 1];
    int e = beg;
    for (; e + 1 < end; e += 2) {   // 2-edge unroll: 2 row-loads in flight
        int s0 = esrc[e], s1 = esrc[e + 1];
        float w0 = dinv[s0], w1 = dinv[s1];
        ushort4 a = ((const ushort4*)xb)[(long)s0 * 64 + lane];
        ushort4 b = ((const ushort4*)xb)[(long)s1 * 64 + lane];
        ax += w0 * bf2f(a.x) + w1 * bf2f(b.x);
        ay += w0 * bf2f(a.y) + w1 * bf2f(b.y);
        az += w0 * bf2f(a.z) + w1 * bf2f(b.z);
        aw += w0 * bf2f(a.w) + w1 * bf2f(b.w);
    }
    if (e < end) {
        int s0 = esrc[e];
        float w0 = dinv[s0];
        ushort4 a = ((const ushort4*)xb)[(long)s0 * 64 + lane];
        ax += w0 * bf2f(a.x); ay += w0 * bf2f(a.y);
        az += w0 * bf2f(a.z); aw += w0 * bf2f(a.w);
    }
    ax *= di; ay *= di; az *= di; aw *= di;
    ushort4 o; o.x = f2bf(ax); o.y = f2bf(ay); o.z = f2bf(az); o.w = f2bf(aw);
    ((ushort4*)aggb)[(long)node * 64 + lane] = o;
}

// ---- prep: transpose both weights to bf16 [N,K], init outacc with bias ----
__global__ void k_prep(const float* __restrict__ W_gcn, unsigned short* __restrict__ Wgt,
                       const float* __restrict__ W2, unsigned short* __restrict__ W2t,
                       const float* __restrict__ b_out, float* __restrict__ outacc, int N) {
    int t = blockIdx.x * blockDim.x + threadIdx.x;
    if (t < D_IN * D_HID) {                       // Wgt [512,256]
        int n = t / D_IN, k = t - n * D_IN;
        Wgt[t] = f2bf(W_gcn[(long)k * D_HID + n]);
        return;
    }
    t -= D_IN * D_HID;
    if (t < D_HID * D_HID) {                      // W2t [512,512]
        int n = t / D_HID, k = t - n * D_HID;
        W2t[t] = f2bf(W2[(long)k * D_HID + n]);
        return;
    }
    t -= D_HID * D_HID;
    if (t < N) outacc[t] = b_out[0];
}

// ---- bf16 MFMA GEMM: C[M,512] = bf16(leaky(A[M,K] @ Bt[512,K]^T + bias)) ----
__device__ __forceinline__ void async_cp16(const unsigned short* gp, unsigned short* lp) {
    __builtin_amdgcn_global_load_lds((const __attribute__((address_space(1))) void*)gp,
                                     (__attribute__((address_space(3))) void*)lp, 16, 0, 0);
}

__global__ __launch_bounds__(256) void k_gemm_bf16(const unsigned short* __restrict__ A,
                                                   const unsigned short* __restrict__ Bt,
                                                   const float* __restrict__ bias,
                                                   unsigned short* __restrict__ C,
                                                   int M, int K) {
    __shared__ __align__(16) unsigned short As[128 * 32];
    __shared__ __align__(16) unsigned short Bs[128 * 32];
    const int tid  = threadIdx.x;
    const int lane = tid & 63, wave = tid >> 6;
    const int m0 = blockIdx.x * 128, n0 = blockIdx.y * 128;
    const int r = lane & 15, q = lane >> 4;
    const int wm = (wave & 1) * 64, wn = (wave >> 1) * 64;

    floatx4 acc[4][4];
#pragma unroll
    for (int i = 0; i < 4; ++i)
#pragma unroll
        for (int j = 0; j < 4; ++j) acc[i][j] = (floatx4){0.f, 0.f, 0.f, 0.f};

    for (int k0 = 0; k0 < K; k0 += 32) {
#pragma unroll
        for (int i = 0; i < 2; ++i) {
            int c = i * 256 + tid;
            int row = c >> 2, qtr = c & 3;
            int gm = m0 + row; if (gm >= M) gm = M - 1;
            async_cp16(A + (long)gm * K + k0 + qtr * 8, As + c * 8);
        }
#pragma unroll
        for (int i = 0; i < 2; ++i) {
            int c = i * 256 + tid;
            int row = c >> 2, qtr = c & 3;
            async_cp16(Bt + (long)(n0 + row) * K + k0 + qtr * 8, Bs + c * 8);
        }
        __syncthreads();

        short8 af[4], bf[4];
#pragma unroll
        for (int i = 0; i < 4; ++i)
            af[i] = *(const short8*)(As + (wm + i * 16 + r) * 32 + q * 8);
#pragma unroll
        for (int j = 0; j < 4; ++j)
            bf[j] = *(const short8*)(Bs + (wn + j * 16 + r) * 32 + q * 8);
#pragma unroll
        for (int i = 0; i < 4; ++i)
#pragma unroll
            for (int j = 0; j < 4; ++j)
                acc[i][j] = __builtin_amdgcn_mfma_f32_16x16x32_bf16(af[i], bf[j], acc[i][j], 0, 0, 0);
        __syncthreads();
    }

    // C/D map: col = lane&15, row = q*4 + reg
#pragma unroll
    for (int j = 0; j < 4; ++j) {
        int col = n0 + wn + j * 16 + r;
        float bv = bias[col];
#pragma unroll
        for (int i = 0; i < 4; ++i) {
#pragma unroll
            for (int t2 = 0; t2 < 4; ++t2) {
                int row = m0 + wm + i * 16 + q * 4 + t2;
                if (row < M) {
                    float v = acc[i][j][t2] + bv;
                    v = v > 0.f ? v : NEG_SLOPE * v;
                    C[(long)row * D_HID + col] = f2bf(v);
                }
            }
        }
    }
}

// ---- GEMM2 fused with head: outacc[row] += sum_col leaky(A@W2t^T + b2) * wout[col] ----
// atomics target ws (coarse device memory), NOT d_out
__global__ __launch_bounds__(256) void k_gemm2f(const unsigned short* __restrict__ A,
                                                const unsigned short* __restrict__ Bt,
                                                const float* __restrict__ bias,
                                                const float* __restrict__ wout,
                                                float* __restrict__ outacc,
                                                int M, int K) {
    __shared__ __align__(16) unsigned short As[128 * 32];
    __shared__ __align__(16) unsigned short Bs[128 * 32];
    const int tid  = threadIdx.x;
    const int lane = tid & 63, wave = tid >> 6;
    const int m0 = blockIdx.x * 128, n0 = blockIdx.y * 128;
    const int r = lane & 15, q = lane >> 4;
    const int wm = (wave & 1) * 64, wn = (wave >> 1) * 64;

    floatx4 acc[4][4];
#pragma unroll
    for (int i = 0; i < 4; ++i)
#pragma unroll
        for (int j = 0; j < 4; ++j) acc[i][j] = (floatx4){0.f, 0.f, 0.f, 0.f};

    for (int k0 = 0; k0 < K; k0 += 32) {
#pragma unroll
        for (int i = 0; i < 2; ++i) {
            int c = i * 256 + tid;
            int row = c >> 2, qtr = c & 3;
            int gm = m0 + row; if (gm >= M) gm = M - 1;
            async_cp16(A + (long)gm * K + k0 + qtr * 8, As + c * 8);
        }
#pragma unroll
        for (int i = 0; i < 2; ++i) {
            int c = i * 256 + tid;
            int row = c >> 2, qtr = c & 3;
            async_cp16(Bt + (long)(n0 + row) * K + k0 + qtr * 8, Bs + c * 8);
        }
        __syncthreads();

        short8 af[4], bf[4];
#pragma unroll
        for (int i = 0; i < 4; ++i)
            af[i] = *(const short8*)(As + (wm + i * 16 + r) * 32 + q * 8);
#pragma unroll
        for (int j = 0; j < 4; ++j)
            bf[j] = *(const short8*)(Bs + (wn + j * 16 + r) * 32 + q * 8);
#pragma unroll
        for (int i = 0; i < 4; ++i)
#pragma unroll
            for (int j = 0; j < 4; ++j)
                acc[i][j] = __builtin_amdgcn_mfma_f32_16x16x32_bf16(af[i], bf[j], acc[i][j], 0, 0, 0);
        __syncthreads();
    }

    // fused epilogue: bias + leaky + dot with wout, reduce over 16 cols/lane-group, atomic per row
    float bv[4], wv[4];
#pragma unroll
    for (int j = 0; j < 4; ++j) {
        int col = n0 + wn + j * 16 + r;
        bv[j] = bias[col];
        wv[j] = wout[col];
    }
#pragma unroll
    for (int i = 0; i < 4; ++i) {
#pragma unroll
        for (int t2 = 0; t2 < 4; ++t2) {
            float p = 0.f;
#pragma unroll
            for (int j = 0; j < 4; ++j) {
                float v = acc[i][j][t2] + bv[j];
                v = v > 0.f ? v : NEG_SLOPE * v;
                p += v * wv[j];
            }
            p += __shfl_xor(p, 8, 64);   // reduce over r within 16-lane q-group
            p += __shfl_xor(p, 4, 64);
            p += __shfl_xor(p, 2, 64);
            p += __shfl_xor(p, 1, 64);
            if (r == 0) {
                int row = m0 + wm + i * 16 + q * 4 + t2;
                if (row < M) atomicAdd(&outacc[row], p);
            }
        }
    }
}

// ---- final: plain-store copy outacc (ws) -> d_out ----
__global__ void k_out(const float* __restrict__ outacc, float* __restrict__ out, int N) {
    int i = blockIdx.x * blockDim.x + threadIdx.x;
    if (i < N) out[i] = outacc[i];
}

extern "C" void kernel_launch(void* const* d_in, const int* in_sizes, int n_in,
                              void* d_out, int out_size, void* d_ws, size_t ws_size,
                              hipStream_t stream) {
    const float* x     = (const float*)d_in[0];
    const void*  ei    = d_in[1];
    const float* W_gcn = (const float*)d_in[2];
    const float* b_gcn = (const float*)d_in[3];
    const float* W2    = (const float*)d_in[4];
    const float* b2    = (const float*)d_in[5];
    const float* W_out = (const float*)d_in[6];
    const float* b_out = (const float*)d_in[7];
    float* out = (float*)d_out;

    const int N = in_sizes[0] / D_IN;
    const int E = in_sizes[1] / 2;

    char* w = (char*)d_ws;
    size_t off = 0;
    auto alloc = [&](size_t bytes) { char* p = w + off; off = (off + bytes + 255) & ~(size_t)255; return p; };
    int*            flag   = (int*)alloc(256);
    float*          dinv   = (float*)alloc((size_t)N * 4);
    int*            deg_i  = (int*)alloc((size_t)N * 4);
    int*            offs   = (int*)alloc((size_t)(N + 1) * 4);
    int*            cursor = (int*)alloc((size_t)N * 4);
    float*          outacc = (float*)alloc((size_t)N * 4);
    int*            esrc   = (int*)alloc((size_t)E * 4);
    unsigned short* xb     = (unsigned short*)alloc((size_t)N * D_IN * 2);
    unsigned short* aggb   = (unsigned short*)alloc((size_t)N * D_IN * 2);
    unsigned short* h1     = (unsigned short*)alloc((size_t)N * D_HID * 2);
    unsigned short* Wgt    = (unsigned short*)alloc((size_t)D_IN * D_HID * 2);
    unsigned short* W2t    = (unsigned short*)alloc((size_t)D_HID * D_HID * 2);

    int npairs = E < 2048 ? E : 2048;
    long xthreads = ((long)N * D_IN) / 4;
    k_init<<<(unsigned)((xthreads + 255) / 256), 256, 0, stream>>>(
        x, xb, deg_i, N, (const unsigned int*)ei, npairs, flag);

    k_deg_count<<<(E + 255) / 256, 256, 0, stream>>>(ei, flag, deg_i, E);
    k_scan<<<1, 1024, 0, stream>>>(deg_i, offs, cursor, dinv, N);
    k_fill<<<(E + 255) / 256, 256, 0, stream>>>(ei, flag, cursor, esrc, E);
    k_gather<<<(N + 3) / 4, 256, 0, stream>>>(xb, offs, esrc, dinv, aggb, N);

    int prep_threads = D_IN * D_HID + D_HID * D_HID + N;
    k_prep<<<(prep_threads + 255) / 256, 256, 0, stream>>>(W_gcn, Wgt, W2, W2t, b_out, outacc, N);

    dim3 g1((N + 127) / 128, D_HID / 128);
    k_gemm_bf16<<<g1, 256, 0, stream>>>(aggb, Wgt, b_gcn, h1, N, D_IN);
    k_gemm2f<<<g1, 256, 0, stream>>>(h1, W2t, b2, W_out, outacc, N, D_HID);

    k_out<<<(N + 255) / 256, 256, 0, stream>>>(outacc, out, N);
}

// Round 7
// 381.422 us; speedup vs baseline: 7.8818x; 1.3118x over previous
//
#include <hip/hip_runtime.h>

#define D_IN  256
#define D_HID 512
#define NEG_SLOPE 0.2f
#define SCAN_CHUNK 2048

typedef __attribute__((ext_vector_type(8))) short short8;
typedef __attribute__((ext_vector_type(4))) float floatx4;

__device__ __forceinline__ unsigned short f2bf(float f) {
    unsigned int u = __float_as_uint(f);
    u += 0x7fffu + ((u >> 16) & 1u);   // round-to-nearest-even
    return (unsigned short)(u >> 16);
}
__device__ __forceinline__ float bf2f(unsigned short u) {
    return __uint_as_float(((unsigned int)u) << 16);
}

__device__ __forceinline__ int eidx(const void* ei, long pos, int is64) {
    return is64 ? (int)((const long long*)ei)[pos] : ((const int*)ei)[pos];
}

// ---- init: convert x -> bf16, zero deg, detect edge dtype (block 0) ----
__global__ __launch_bounds__(256) void k_init(const float* __restrict__ x,
                                              unsigned short* __restrict__ xb,
                                              int* __restrict__ deg, int N,
                                              const unsigned int* __restrict__ ei,
                                              int npairs, int* flag) {
    long t = (long)blockIdx.x * blockDim.x + threadIdx.x;
    long i = t * 4;
    long tot = (long)N * D_IN;
    if (i < tot) {
        float4 v = *(const float4*)(x + i);
        ushort4 o;
        o.x = f2bf(v.x); o.y = f2bf(v.y); o.z = f2bf(v.z); o.w = f2bf(v.w);
        *(ushort4*)(xb + i) = o;
    }
    if (t < N) deg[t] = 0;
    if (blockIdx.x == 0) {
        __shared__ int nz;
        if (threadIdx.x == 0) nz = 0;
        __syncthreads();
        for (int p = threadIdx.x; p < npairs; p += blockDim.x)
            if (ei[2 * p + 1] != 0) nz = 1;
        __syncthreads();
        if (threadIdx.x == 0) *flag = nz ? 0 : 1;   // 1 => int64
    }
}

// ---- degree count (int only) ----
__global__ void k_deg_count(const void* __restrict__ ei, const int* __restrict__ flag,
                            int* __restrict__ deg, int E) {
    int e = blockIdx.x * blockDim.x + threadIdx.x;
    if (e < E) atomicAdd(&deg[eidx(ei, (long)E + e, *flag)], 1);
}

// ---- hierarchical scan, phase 1: per-chunk sums ----
__global__ __launch_bounds__(256) void k_scan1(const int* __restrict__ deg,
                                               int* __restrict__ bsum, int N) {
    int base = blockIdx.x * SCAN_CHUNK;
    int hi = min(base + SCAN_CHUNK, N);
    int s = 0;
    for (int i = base + threadIdx.x; i < hi; i += 256) s += deg[i];
#pragma unroll
    for (int off = 32; off > 0; off >>= 1) s += __shfl_down(s, off, 64);
    __shared__ int lds[4];
    if ((threadIdx.x & 63) == 0) lds[threadIdx.x >> 6] = s;
    __syncthreads();
    if (threadIdx.x == 0) bsum[blockIdx.x] = lds[0] + lds[1] + lds[2] + lds[3];
}

// ---- phase 2: scan the (tiny) block sums; write per-block bases + offs[N] ----
__global__ __launch_bounds__(1024) void k_scan2(const int* __restrict__ bsum,
                                                int* __restrict__ bbase,
                                                int* __restrict__ offs, int NB, int N) {
    __shared__ int lds[1024];
    int t = threadIdx.x;
    lds[t] = (t < NB) ? bsum[t] : 0;
    __syncthreads();
    for (int d = 1; d < 1024; d <<= 1) {
        int add = (t >= d) ? lds[t - d] : 0;
        __syncthreads();
        lds[t] += add;
        __syncthreads();
    }
    if (t < NB) bbase[t] = (t > 0) ? lds[t - 1] : 0;
    if (t == 0) offs[N] = lds[NB - 1];
}

// ---- phase 3: block-local scan, write offs/cursor/dinv ----
__global__ __launch_bounds__(256) void k_scan3(const int* __restrict__ deg,
                                               const int* __restrict__ bbase,
                                               int* __restrict__ offs,
                                               int* __restrict__ cursor,
                                               float* __restrict__ dinv, int N) {
    __shared__ int lds[256];
    int base = blockIdx.x * SCAN_CHUNK;
    int t = threadIdx.x;
    int lo = base + t * 8;
    int v[8], s = 0;
#pragma unroll
    for (int j = 0; j < 8; ++j) {
        int i = lo + j;
        v[j] = (i < N) ? deg[i] : 0;
        s += v[j];
    }
    lds[t] = s;
    __syncthreads();
    for (int d = 1; d < 256; d <<= 1) {
        int add = (t >= d) ? lds[t - d] : 0;
        __syncthreads();
        lds[t] += add;
        __syncthreads();
    }
    int run = bbase[blockIdx.x] + ((t > 0) ? lds[t - 1] : 0);
#pragma unroll
    for (int j = 0; j < 8; ++j) {
        int i = lo + j;
        if (i < N) {
            offs[i] = run; cursor[i] = run;
            dinv[i] = rsqrtf(1.0f + (float)v[j]);
            run += v[j];
        }
    }
}

// ---- fill CSR edge list (src per slot, dst-sorted) ----
__global__ void k_fill(const void* __restrict__ ei, const int* __restrict__ flag,
                       int* __restrict__ cursor, int* __restrict__ esrc, int E) {
    int e = blockIdx.x * blockDim.x + threadIdx.x;
    if (e >= E) return;
    int is64 = *flag;
    int s = eidx(ei, e, is64), d = eidx(ei, (long)E + e, is64);
    int pos = atomicAdd(&cursor[d], 1);
    esrc[pos] = s;
}

// ---- gather (bf16 rows): aggb[i] = bf16( dinv_i*(dinv_i*xb[i] + sum dinv_s*xb[s]) ) ----
__global__ __launch_bounds__(256) void k_gather(const unsigned short* __restrict__ xb,
                                                const int* __restrict__ offs,
                                                const int* __restrict__ esrc,
                                                const float* __restrict__ dinv,
                                                unsigned short* __restrict__ aggb, int N) {
    int node = blockIdx.x * 4 + (threadIdx.x >> 6);
    int lane = threadIdx.x & 63;
    if (node >= N) return;
    float di = dinv[node];
    ushort4 u0 = ((const ushort4*)xb)[(long)node * 64 + lane];
    float ax = di * bf2f(u0.x), ay = di * bf2f(u0.y), az = di * bf2f(u0.z), aw = di * bf2f(u0.w);
    int beg = offs[node], end = offs[node + 1];
    int e = beg;
    for (; e + 1 < end; e += 2) {   // 2-edge unroll: 2 row-loads in flight
        int s0 = esrc[e], s1 = esrc[e + 1];
        float w0 = dinv[s0], w1 = dinv[s1];
        ushort4 a = ((const ushort4*)xb)[(long)s0 * 64 + lane];
        ushort4 b = ((const ushort4*)xb)[(long)s1 * 64 + lane];
        ax += w0 * bf2f(a.x) + w1 * bf2f(b.x);
        ay += w0 * bf2f(a.y) + w1 * bf2f(b.y);
        az += w0 * bf2f(a.z) + w1 * bf2f(b.z);
        aw += w0 * bf2f(a.w) + w1 * bf2f(b.w);
    }
    if (e < end) {
        int s0 = esrc[e];
        float w0 = dinv[s0];
        ushort4 a = ((const ushort4*)xb)[(long)s0 * 64 + lane];
        ax += w0 * bf2f(a.x); ay += w0 * bf2f(a.y);
        az += w0 * bf2f(a.z); aw += w0 * bf2f(a.w);
    }
    ax *= di; ay *= di; az *= di; aw *= di;
    ushort4 o; o.x = f2bf(ax); o.y = f2bf(ay); o.z = f2bf(az); o.w = f2bf(aw);
    ((ushort4*)aggb)[(long)node * 64 + lane] = o;
}

// ---- prep: transpose both weights to bf16 [N,K], init outacc with bias ----
__global__ void k_prep(const float* __restrict__ W_gcn, unsigned short* __restrict__ Wgt,
                       const float* __restrict__ W2, unsigned short* __restrict__ W2t,
                       const float* __restrict__ b_out, float* __restrict__ outacc, int N) {
    int t = blockIdx.x * blockDim.x + threadIdx.x;
    if (t < D_IN * D_HID) {                       // Wgt [512,256]
        int n = t / D_IN, k = t - n * D_IN;
        Wgt[t] = f2bf(W_gcn[(long)k * D_HID + n]);
        return;
    }
    t -= D_IN * D_HID;
    if (t < D_HID * D_HID) {                      // W2t [512,512]
        int n = t / D_HID, k = t - n * D_HID;
        W2t[t] = f2bf(W2[(long)k * D_HID + n]);
        return;
    }
    t -= D_HID * D_HID;
    if (t < N) outacc[t] = b_out[0];
}

// ---- bf16 MFMA GEMM: C[M,512] = bf16(leaky(A[M,K] @ Bt[512,K]^T + bias)) ----
__device__ __forceinline__ void async_cp16(const unsigned short* gp, unsigned short* lp) {
    __builtin_amdgcn_global_load_lds((const __attribute__((address_space(1))) void*)gp,
                                     (__attribute__((address_space(3))) void*)lp, 16, 0, 0);
}

__global__ __launch_bounds__(256) void k_gemm_bf16(const unsigned short* __restrict__ A,
                                                   const unsigned short* __restrict__ Bt,
                                                   const float* __restrict__ bias,
                                                   unsigned short* __restrict__ C,
                                                   int M, int K) {
    __shared__ __align__(16) unsigned short As[128 * 32];
    __shared__ __align__(16) unsigned short Bs[128 * 32];
    const int tid  = threadIdx.x;
    const int lane = tid & 63, wave = tid >> 6;
    const int m0 = blockIdx.x * 128, n0 = blockIdx.y * 128;
    const int r = lane & 15, q = lane >> 4;
    const int wm = (wave & 1) * 64, wn = (wave >> 1) * 64;

    floatx4 acc[4][4];
#pragma unroll
    for (int i = 0; i < 4; ++i)
#pragma unroll
        for (int j = 0; j < 4; ++j) acc[i][j] = (floatx4){0.f, 0.f, 0.f, 0.f};

    for (int k0 = 0; k0 < K; k0 += 32) {
#pragma unroll
        for (int i = 0; i < 2; ++i) {
            int c = i * 256 + tid;
            int row = c >> 2, qtr = c & 3;
            int gm = m0 + row; if (gm >= M) gm = M - 1;
            async_cp16(A + (long)gm * K + k0 + qtr * 8, As + c * 8);
        }
#pragma unroll
        for (int i = 0; i < 2; ++i) {
            int c = i * 256 + tid;
            int row = c >> 2, qtr = c & 3;
            async_cp16(Bt + (long)(n0 + row) * K + k0 + qtr * 8, Bs + c * 8);
        }
        __syncthreads();

        short8 af[4], bf[4];
#pragma unroll
        for (int i = 0; i < 4; ++i)
            af[i] = *(const short8*)(As + (wm + i * 16 + r) * 32 + q * 8);
#pragma unroll
        for (int j = 0; j < 4; ++j)
            bf[j] = *(const short8*)(Bs + (wn + j * 16 + r) * 32 + q * 8);
#pragma unroll
        for (int i = 0; i < 4; ++i)
#pragma unroll
            for (int j = 0; j < 4; ++j)
                acc[i][j] = __builtin_amdgcn_mfma_f32_16x16x32_bf16(af[i], bf[j], acc[i][j], 0, 0, 0);
        __syncthreads();
    }

    // C/D map: col = lane&15, row = q*4 + reg
#pragma unroll
    for (int j = 0; j < 4; ++j) {
        int col = n0 + wn + j * 16 + r;
        float bv = bias[col];
#pragma unroll
        for (int i = 0; i < 4; ++i) {
#pragma unroll
            for (int t2 = 0; t2 < 4; ++t2) {
                int row = m0 + wm + i * 16 + q * 4 + t2;
                if (row < M) {
                    float v = acc[i][j][t2] + bv;
                    v = v > 0.f ? v : NEG_SLOPE * v;
                    C[(long)row * D_HID + col] = f2bf(v);
                }
            }
        }
    }
}

// ---- GEMM2 fused with head: outacc[row] += sum_col leaky(A@W2t^T + b2) * wout[col] ----
// atomics target ws (coarse device memory), NOT d_out
__global__ __launch_bounds__(256) void k_gemm2f(const unsigned short* __restrict__ A,
                                                const unsigned short* __restrict__ Bt,
                                                const float* __restrict__ bias,
                                                const float* __restrict__ wout,
                                                float* __restrict__ outacc,
                                                int M, int K) {
    __shared__ __align__(16) unsigned short As[128 * 32];
    __shared__ __align__(16) unsigned short Bs[128 * 32];
    const int tid  = threadIdx.x;
    const int lane = tid & 63, wave = tid >> 6;
    const int m0 = blockIdx.x * 128, n0 = blockIdx.y * 128;
    const int r = lane & 15, q = lane >> 4;
    const int wm = (wave & 1) * 64, wn = (wave >> 1) * 64;

    floatx4 acc[4][4];
#pragma unroll
    for (int i = 0; i < 4; ++i)
#pragma unroll
        for (int j = 0; j < 4; ++j) acc[i][j] = (floatx4){0.f, 0.f, 0.f, 0.f};

    for (int k0 = 0; k0 < K; k0 += 32) {
#pragma unroll
        for (int i = 0; i < 2; ++i) {
            int c = i * 256 + tid;
            int row = c >> 2, qtr = c & 3;
            int gm = m0 + row; if (gm >= M) gm = M - 1;
            async_cp16(A + (long)gm * K + k0 + qtr * 8, As + c * 8);
        }
#pragma unroll
        for (int i = 0; i < 2; ++i) {
            int c = i * 256 + tid;
            int row = c >> 2, qtr = c & 3;
            async_cp16(Bt + (long)(n0 + row) * K + k0 + qtr * 8, Bs + c * 8);
        }
        __syncthreads();

        short8 af[4], bf[4];
#pragma unroll
        for (int i = 0; i < 4; ++i)
            af[i] = *(const short8*)(As + (wm + i * 16 + r) * 32 + q * 8);
#pragma unroll
        for (int j = 0; j < 4; ++j)
            bf[j] = *(const short8*)(Bs + (wn + j * 16 + r) * 32 + q * 8);
#pragma unroll
        for (int i = 0; i < 4; ++i)
#pragma unroll
            for (int j = 0; j < 4; ++j)
                acc[i][j] = __builtin_amdgcn_mfma_f32_16x16x32_bf16(af[i], bf[j], acc[i][j], 0, 0, 0);
        __syncthreads();
    }

    // fused epilogue: bias + leaky + dot with wout, reduce over 16 cols/lane-group, atomic per row
    float bv[4], wv[4];
#pragma unroll
    for (int j = 0; j < 4; ++j) {
        int col = n0 + wn + j * 16 + r;
        bv[j] = bias[col];
        wv[j] = wout[col];
    }
#pragma unroll
    for (int i = 0; i < 4; ++i) {
#pragma unroll
        for (int t2 = 0; t2 < 4; ++t2) {
            float p = 0.f;
#pragma unroll
            for (int j = 0; j < 4; ++j) {
                float v = acc[i][j][t2] + bv[j];
                v = v > 0.f ? v : NEG_SLOPE * v;
                p += v * wv[j];
            }
            p += __shfl_xor(p, 8, 64);   // reduce over r within 16-lane q-group
            p += __shfl_xor(p, 4, 64);
            p += __shfl_xor(p, 2, 64);
            p += __shfl_xor(p, 1, 64);
            if (r == 0) {
                int row = m0 + wm + i * 16 + q * 4 + t2;
                if (row < M) atomicAdd(&outacc[row], p);
            }
        }
    }
}

// ---- final: plain-store copy outacc (ws) -> d_out ----
__global__ void k_out(const float* __restrict__ outacc, float* __restrict__ out, int N) {
    int i = blockIdx.x * blockDim.x + threadIdx.x;
    if (i < N) out[i] = outacc[i];
}

extern "C" void kernel_launch(void* const* d_in, const int* in_sizes, int n_in,
                              void* d_out, int out_size, void* d_ws, size_t ws_size,
                              hipStream_t stream) {
    const float* x     = (const float*)d_in[0];
    const void*  ei    = d_in[1];
    const float* W_gcn = (const float*)d_in[2];
    const float* b_gcn = (const float*)d_in[3];
    const float* W2    = (const float*)d_in[4];
    const float* b2    = (const float*)d_in[5];
    const float* W_out = (const float*)d_in[6];
    const float* b_out = (const float*)d_in[7];
    float* out = (float*)d_out;

    const int N = in_sizes[0] / D_IN;
    const int E = in_sizes[1] / 2;
    const int NB = (N + SCAN_CHUNK - 1) / SCAN_CHUNK;

    char* w = (char*)d_ws;
    size_t off = 0;
    auto alloc = [&](size_t bytes) { char* p = w + off; off = (off + bytes + 255) & ~(size_t)255; return p; };
    int*            flag   = (int*)alloc(256);
    float*          dinv   = (float*)alloc((size_t)N * 4);
    int*            deg_i  = (int*)alloc((size_t)N * 4);
    int*            offs   = (int*)alloc((size_t)(N + 1) * 4);
    int*            cursor = (int*)alloc((size_t)N * 4);
    float*          outacc = (float*)alloc((size_t)N * 4);
    int*            bsum   = (int*)alloc((size_t)NB * 4);
    int*            bbase  = (int*)alloc((size_t)NB * 4);
    int*            esrc   = (int*)alloc((size_t)E * 4);
    unsigned short* xb     = (unsigned short*)alloc((size_t)N * D_IN * 2);
    unsigned short* aggb   = (unsigned short*)alloc((size_t)N * D_IN * 2);
    unsigned short* h1     = (unsigned short*)alloc((size_t)N * D_HID * 2);
    unsigned short* Wgt    = (unsigned short*)alloc((size_t)D_IN * D_HID * 2);
    unsigned short* W2t    = (unsigned short*)alloc((size_t)D_HID * D_HID * 2);

    int npairs = E < 2048 ? E : 2048;
    long xthreads = ((long)N * D_IN) / 4;
    k_init<<<(unsigned)((xthreads + 255) / 256), 256, 0, stream>>>(
        x, xb, deg_i, N, (const unsigned int*)ei, npairs, flag);

    k_deg_count<<<(E + 255) / 256, 256, 0, stream>>>(ei, flag, deg_i, E);
    k_scan1<<<NB, 256, 0, stream>>>(deg_i, bsum, N);
    k_scan2<<<1, 1024, 0, stream>>>(bsum, bbase, offs, NB, N);
    k_scan3<<<NB, 256, 0, stream>>>(deg_i, bbase, offs, cursor, dinv, N);
    k_fill<<<(E + 255) / 256, 256, 0, stream>>>(ei, flag, cursor, esrc, E);
    k_gather<<<(N + 3) / 4, 256, 0, stream>>>(xb, offs, esrc, dinv, aggb, N);

    int prep_threads = D_IN * D_HID + D_HID * D_HID + N;
    k_prep<<<(prep_threads + 255) / 256, 256, 0, stream>>>(W_gcn, Wgt, W2, W2t, b_out, outacc, N);

    dim3 g1((N + 127) / 128, D_HID / 128);
    k_gemm_bf16<<<g1, 256, 0, stream>>>(aggb, Wgt, b_gcn, h1, N, D_IN);
    k_gemm2f<<<g1, 256, 0, stream>>>(h1, W2t, b2, W_out, outacc, N, D_HID);

    k_out<<<(N + 255) / 256, 256, 0, stream>>>(outacc, out, N);
}